// Round 1
// baseline (315.964 us; speedup 1.0000x reference)
//
#include <hip/hip_runtime.h>
#include <stdint.h>

// CrossNetwork: x:[16384,512] f32, W:[4,512,512] f32 (torch Linear), b:[4,512] f32
// out:[16384, 4*512] f32 = concat of layer outputs.
//
// Algebra: the scalar-residual loop collapses to x_eff = x_i + c_i*1 with
//   c = 0; for j<i: c += dot(x_i,x_j) + c*sum(x_j)
// and (x_i + c*1) @ W^T = x_i @ W^T + c * rowsum(W). So: 4 bf16 MFMA GEMMs +
// per-row scalar stats + rank-1 epilogue.

#define BROWS 16384
#define DIM 512
#define NL 4
#define OUTSTRIDE (NL * DIM)

#define BM 128
#define BN 128
#define BK 32

typedef unsigned short ushort_t;
typedef __attribute__((ext_vector_type(8))) short bf16x8;
typedef __attribute__((ext_vector_type(4))) float f32x4;

__device__ inline ushort_t f32_to_bf16(float f) {
    union { float f; uint32_t u; } v; v.f = f;
    uint32_t u = v.u;
    // round-to-nearest-even
    uint32_t r = (u + 0x7fffu + ((u >> 16) & 1u)) >> 16;
    return (ushort_t)r;
}

__device__ inline float wave_reduce_sum(float v) {
    #pragma unroll
    for (int off = 32; off > 0; off >>= 1) v += __shfl_down(v, off, 64);
    return v;
}

// ---------------------------------------------------------------------------
// convw: W f32 -> bf16, plus wsum[l][e] = sum_d W[l][e][d]
// grid: 4*512 blocks (one per W row), 256 threads
// ---------------------------------------------------------------------------
__global__ __launch_bounds__(256) void convw_kernel(
    const float* __restrict__ W, ushort_t* __restrict__ Wb,
    float* __restrict__ wsum)
{
    int row = blockIdx.x;      // l*512 + e
    int t = threadIdx.x;
    const float* wp = W + (size_t)row * DIM;
    float f0 = wp[2 * t], f1 = wp[2 * t + 1];
    ushort_t* wbp = Wb + (size_t)row * DIM;
    wbp[2 * t]     = f32_to_bf16(f0);
    wbp[2 * t + 1] = f32_to_bf16(f1);
    __shared__ float red[4];
    int wave = t >> 6, lane = t & 63;
    float r = wave_reduce_sum(f0 + f1);
    if (lane == 0) red[wave] = r;
    __syncthreads();
    if (t == 0) wsum[row] = red[0] + red[1] + red[2] + red[3];
}

// ---------------------------------------------------------------------------
// stats: for activation layer i (i=0 => input x), per row b:
//   - bf16 copy into xb[i]
//   - sums[i][b] = sum_d x_i[b][d]
//   - for i>0: dots with x_j (j<i) and the sequential c-chain -> cvals[i][b]
// grid: 16384 blocks, 256 threads (2 elems/thread)
// ---------------------------------------------------------------------------
__global__ __launch_bounds__(256) void stats_kernel(
    const float* __restrict__ x0, const float* __restrict__ out,
    ushort_t* __restrict__ xb, float* __restrict__ sums,
    float* __restrict__ cvals, int layer)
{
    int b = blockIdx.x;
    int t = threadIdx.x;
    const float* xi = (layer == 0) ? (x0 + (size_t)b * DIM)
                                   : (out + (size_t)b * OUTSTRIDE + (size_t)(layer - 1) * DIM);
    float f0 = xi[2 * t], f1 = xi[2 * t + 1];
    ushort_t* xbp = xb + (size_t)layer * BROWS * DIM + (size_t)b * DIM;
    xbp[2 * t]     = f32_to_bf16(f0);
    xbp[2 * t + 1] = f32_to_bf16(f1);

    float vals[4];
    vals[0] = f0 + f1;
    vals[1] = vals[2] = vals[3] = 0.f;
    for (int j = 0; j < layer; ++j) {
        const float* xj = (j == 0) ? (x0 + (size_t)b * DIM)
                                   : (out + (size_t)b * OUTSTRIDE + (size_t)(j - 1) * DIM);
        float g0 = xj[2 * t], g1 = xj[2 * t + 1];
        vals[1 + j] = f0 * g0 + f1 * g1;
    }

    __shared__ float red[4][4];   // [wave][value]
    int wave = t >> 6, lane = t & 63;
    #pragma unroll
    for (int v = 0; v < 4; ++v) {
        float r = wave_reduce_sum(vals[v]);
        if (lane == 0) red[wave][v] = r;
    }
    __syncthreads();
    if (t == 0) {
        float tot[4];
        #pragma unroll
        for (int v = 0; v < 4; ++v)
            tot[v] = red[0][v] + red[1][v] + red[2][v] + red[3][v];
        sums[layer * BROWS + b] = tot[0];
        if (layer > 0) {
            float c = 0.f;
            for (int j = 0; j < layer; ++j)
                c = c + tot[1 + j] + c * sums[j * BROWS + b];
            cvals[layer * BROWS + b] = c;
        }
    }
}

// ---------------------------------------------------------------------------
// GEMM: y[b][e] = sum_d A[b][d]*Wb[e][d] + c[b]*wsum[e] + bias[e]
// m97-verified structure: 128x128 tile, 4 waves (2x2), each 4x4 of 16x16x32,
// global_load_lds width 16, single-buffered LDS, BK=32.
// grid: (N/128=4, M/128=128), 256 threads.
// ---------------------------------------------------------------------------
__global__ __launch_bounds__(256) void gemm_kernel(
    const ushort_t* __restrict__ A,    // [16384][512] bf16 bits
    const ushort_t* __restrict__ Wb,   // [512][512] bf16 bits, row-major [e][d]
    const float* __restrict__ bias,    // [512]
    const float* __restrict__ wsum,    // [512]
    const float* __restrict__ cvals,   // [16384] or nullptr
    float* __restrict__ out)           // stride OUTSTRIDE, already column-offset
{
    __shared__ __align__(16) ushort_t sA[BM * BK];
    __shared__ __align__(16) ushort_t sB[BN * BK];

    int tid  = threadIdx.x;
    int wave = tid >> 6;
    int lane = tid & 63;
    int wm = wave >> 1, wn = wave & 1;   // 2x2 wave grid
    int bm = blockIdx.y * BM;
    int bn = blockIdx.x * BN;

    f32x4 acc[4][4] = {};

    int srow = lane >> 2;            // 0..15: row within 16-row staging chunk
    int scol = (lane & 3) * 8;       // 0,8,16,24: elem col

    for (int k0 = 0; k0 < DIM; k0 += BK) {
        __syncthreads();   // previous iteration's LDS reads complete
        #pragma unroll
        for (int t2 = 0; t2 < 2; ++t2) {
            int r = wave * 32 + t2 * 16;                     // wave-uniform
            const ushort_t* gA = A  + (size_t)(bm + r + srow) * DIM + k0 + scol;
            const ushort_t* gB = Wb + (size_t)(bn + r + srow) * DIM + k0 + scol;
            __builtin_amdgcn_global_load_lds(
                (const __attribute__((address_space(1))) void*)gA,
                (__attribute__((address_space(3))) void*)(sA + r * BK), 16, 0, 0);
            __builtin_amdgcn_global_load_lds(
                (const __attribute__((address_space(1))) void*)gB,
                (__attribute__((address_space(3))) void*)(sB + r * BK), 16, 0, 0);
        }
        __syncthreads();   // drains vmcnt(0) before barrier => LDS ready

        int q = lane >> 4;        // quad 0..3 -> k-offset q*8
        int rr = lane & 15;       // row within 16
        bf16x8 af[4], bfr[4];
        #pragma unroll
        for (int mi = 0; mi < 4; ++mi)
            af[mi] = *(const bf16x8*)(sA + (wm * 64 + mi * 16 + rr) * BK + q * 8);
        #pragma unroll
        for (int ni = 0; ni < 4; ++ni)
            bfr[ni] = *(const bf16x8*)(sB + (wn * 64 + ni * 16 + rr) * BK + q * 8);
        #pragma unroll
        for (int mi = 0; mi < 4; ++mi)
            #pragma unroll
            for (int ni = 0; ni < 4; ++ni)
                acc[mi][ni] = __builtin_amdgcn_mfma_f32_16x16x32_bf16(
                    af[mi], bfr[ni], acc[mi][ni], 0, 0, 0);
    }

    // Epilogue. C/D layout (verified m89/m91): col = lane&15, row = (lane>>4)*4 + reg
    int q = lane >> 4, nlane = lane & 15;
    #pragma unroll
    for (int ni = 0; ni < 4; ++ni) {
        int n_g = bn + wn * 64 + ni * 16 + nlane;
        float ws = wsum[n_g];
        float bs = bias[n_g];
        #pragma unroll
        for (int mi = 0; mi < 4; ++mi) {
            int m_base = bm + wm * 64 + mi * 16 + q * 4;
            #pragma unroll
            for (int r = 0; r < 4; ++r) {
                int m_g = m_base + r;
                float c = cvals ? cvals[m_g] : 0.f;
                out[(size_t)m_g * OUTSTRIDE + n_g] = acc[mi][ni][r] + c * ws + bs;
            }
        }
    }
}

// ---------------------------------------------------------------------------
extern "C" void kernel_launch(void* const* d_in, const int* in_sizes, int n_in,
                              void* d_out, int out_size, void* d_ws, size_t ws_size,
                              hipStream_t stream) {
    (void)in_sizes; (void)n_in; (void)out_size; (void)ws_size;
    const float* x0   = (const float*)d_in[0];
    const float* W    = (const float*)d_in[1];
    const float* bias = (const float*)d_in[2];
    float* out = (float*)d_out;

    char* ws = (char*)d_ws;
    // workspace layout (bytes):
    //   xb   : 4 * 16384*512 * 2 = 67,108,864
    //   Wb   : 4 * 512*512  * 2 =  2,097,152
    //   wsum : 4 * 512 * 4      =      8,192
    //   sums : 4 * 16384 * 4    =    262,144
    //   cvals: 4 * 16384 * 4    =    262,144   (~66.5 MB total)
    ushort_t* xb   = (ushort_t*)ws;
    ushort_t* Wb   = (ushort_t*)(ws + 67108864);
    float*    wsum = (float*)   (ws + 69206016);
    float*    sums = (float*)   (ws + 69214208);
    float*    cvals= (float*)   (ws + 69476352);

    convw_kernel<<<NL * DIM, 256, 0, stream>>>(W, Wb, wsum);

    dim3 ggrid(DIM / BN, BROWS / BM);   // (4, 128)
    for (int l = 0; l < NL; ++l) {
        stats_kernel<<<BROWS, 256, 0, stream>>>(x0, out, xb, sums, cvals, l);
        gemm_kernel<<<ggrid, 256, 0, stream>>>(
            xb + (size_t)l * BROWS * DIM,
            Wb + (size_t)l * DIM * DIM,
            bias + l * DIM,
            wsum + l * DIM,
            (l > 0) ? (cvals + l * BROWS) : nullptr,
            out + l * DIM);
    }
}

// Round 2
// 291.825 us; speedup vs baseline: 1.0827x; 1.0827x over previous
//
#include <hip/hip_runtime.h>
#include <stdint.h>

// CrossNetwork: x:[16384,512] f32, W:[4,512,512] f32 (torch Linear), b:[4,512] f32
// out:[16384, 4*512] f32 = concat of layer outputs.
//
// Algebra: the scalar-residual loop collapses to x_eff = x_i + c_i*1 with
//   c = 0; for j<i: c += dot(x_i,x_j) + c*sum(x_j)
// and (x_i + c*1) @ W^T = x_i @ W^T + c * rowsum(W). So: 4 bf16 MFMA GEMMs +
// per-row scalar stats + rank-1 epilogue.
//
// R2 structure: GEMM epilogue emits BOTH f32 out and bf16 xb_{l+1} (kills the
// separate conversion pass); dots kernel reads bf16 (half the bytes of R1's
// f32 stats) with one bf16x8 load per row per layer.

#define BROWS 16384
#define DIM 512
#define NL 4
#define OUTSTRIDE (NL * DIM)

#define BM 128
#define BN 128
#define BK 32

typedef unsigned short ushort_t;
typedef __attribute__((ext_vector_type(8))) short bf16x8;
typedef __attribute__((ext_vector_type(4))) float f32x4;

__device__ inline ushort_t f32_to_bf16(float f) {
    union { float f; uint32_t u; } v; v.f = f;
    uint32_t u = v.u;
    uint32_t r = (u + 0x7fffu + ((u >> 16) & 1u)) >> 16;   // RNE
    return (ushort_t)r;
}

__device__ inline float bf16_bits_to_f32(ushort_t u) {
    union { uint32_t u; float f; } v; v.u = ((uint32_t)u) << 16; return v.f;
}

__device__ inline float wave_reduce_sum(float v) {
    #pragma unroll
    for (int off = 32; off > 0; off >>= 1) v += __shfl_down(v, off, 64);
    return v;
}

// ---------------------------------------------------------------------------
// convw: W f32 -> bf16, plus wsum[l][e] = sum_d W[l][e][d]
// grid: 4*512 blocks (one per W row), 256 threads
// ---------------------------------------------------------------------------
__global__ __launch_bounds__(256) void convw_kernel(
    const float* __restrict__ W, ushort_t* __restrict__ Wb,
    float* __restrict__ wsum)
{
    int row = blockIdx.x;      // l*512 + e
    int t = threadIdx.x;
    const float* wp = W + (size_t)row * DIM;
    float f0 = wp[2 * t], f1 = wp[2 * t + 1];
    ushort_t* wbp = Wb + (size_t)row * DIM;
    wbp[2 * t]     = f32_to_bf16(f0);
    wbp[2 * t + 1] = f32_to_bf16(f1);
    __shared__ float red[4];
    int wave = t >> 6, lane = t & 63;
    float r = wave_reduce_sum(f0 + f1);
    if (lane == 0) red[wave] = r;
    __syncthreads();
    if (t == 0) wsum[row] = red[0] + red[1] + red[2] + red[3];
}

// ---------------------------------------------------------------------------
// conv0: x0 f32 -> bf16 xb0, plus sums[0][b]. One wave per row (lane: 8 elems).
// grid: 16384/4 blocks, 256 threads.
// ---------------------------------------------------------------------------
__global__ __launch_bounds__(256) void conv0_kernel(
    const float* __restrict__ x0, ushort_t* __restrict__ xb0,
    float* __restrict__ sums)
{
    int wave = threadIdx.x >> 6, lane = threadIdx.x & 63;
    int b = blockIdx.x * 4 + wave;
    const float* xp = x0 + (size_t)b * DIM + lane * 8;
    float4 a = ((const float4*)xp)[0];
    float4 c4 = ((const float4*)xp)[1];
    float f[8] = {a.x, a.y, a.z, a.w, c4.x, c4.y, c4.z, c4.w};
    bf16x8 o;
    float s = 0.f;
    #pragma unroll
    for (int i = 0; i < 8; ++i) {
        o[i] = (short)f32_to_bf16(f[i]);
        s += f[i];
    }
    *(bf16x8*)(xb0 + (size_t)b * DIM + lane * 8) = o;
    s = wave_reduce_sum(s);
    if (lane == 0) sums[b] = s;
}

// ---------------------------------------------------------------------------
// dots: after GEMM-l produced xb[lp1]: per row b compute
//   sums[lp1][b] = sum(x_{lp1}),  dot(x_{lp1}, x_j) j<lp1,  then the c-chain
//   cvals[lp1][b] = fold(c + dot + c*sums_j).
// One wave per row; bf16x8 loads. grid: 16384/4 blocks, 256 threads.
// ---------------------------------------------------------------------------
__global__ __launch_bounds__(256) void dots_kernel(
    const ushort_t* __restrict__ xb, float* __restrict__ sums,
    float* __restrict__ cvals, int lp1)
{
    int wave = threadIdx.x >> 6, lane = threadIdx.x & 63;
    int b = blockIdx.x * 4 + wave;
    bf16x8 v = *(const bf16x8*)(xb + ((size_t)lp1 * BROWS + b) * DIM + lane * 8);
    float xi[8];
    float ssum = 0.f;
    #pragma unroll
    for (int i = 0; i < 8; ++i) {
        xi[i] = bf16_bits_to_f32((ushort_t)v[i]);
        ssum += xi[i];
    }
    float dots[3] = {0.f, 0.f, 0.f};
    #pragma unroll
    for (int j = 0; j < 3; ++j) {
        if (j < lp1) {
            bf16x8 w = *(const bf16x8*)(xb + ((size_t)j * BROWS + b) * DIM + lane * 8);
            float d = 0.f;
            #pragma unroll
            for (int i = 0; i < 8; ++i)
                d += xi[i] * bf16_bits_to_f32((ushort_t)w[i]);
            dots[j] = d;
        }
    }
    ssum = wave_reduce_sum(ssum);
    #pragma unroll
    for (int j = 0; j < 3; ++j)
        dots[j] = wave_reduce_sum(dots[j]);
    if (lane == 0) {
        sums[lp1 * BROWS + b] = ssum;
        float c = 0.f;
        for (int j = 0; j < lp1; ++j)
            c = c + dots[j] + c * sums[j * BROWS + b];
        cvals[lp1 * BROWS + b] = c;
    }
}

// ---------------------------------------------------------------------------
// GEMM: y[b][e] = sum_d A[b][d]*Wb[e][d] + c[b]*wsum[e] + bias[e]
// Writes f32 out AND (optionally) bf16 xb_next for the next layer.
// m97-verified structure: 128x128 tile, 4 waves (2x2), each 4x4 of 16x16x32,
// global_load_lds width 16, single-buffered LDS, BK=32.
// grid: (N/128=4, M/128=128), 256 threads.
// ---------------------------------------------------------------------------
__global__ __launch_bounds__(256) void gemm_kernel(
    const ushort_t* __restrict__ A,    // [16384][512] bf16 bits
    const ushort_t* __restrict__ Wb,   // [512][512] bf16 bits, row-major [e][d]
    const float* __restrict__ bias,    // [512]
    const float* __restrict__ wsum,    // [512]
    const float* __restrict__ cvals,   // [16384] or nullptr
    float* __restrict__ out,           // stride OUTSTRIDE, already column-offset
    ushort_t* __restrict__ xb_next)    // [16384][512] bf16 or nullptr
{
    __shared__ __align__(16) ushort_t sA[BM * BK];
    __shared__ __align__(16) ushort_t sB[BN * BK];

    int tid  = threadIdx.x;
    int wave = tid >> 6;
    int lane = tid & 63;
    int wm = wave >> 1, wn = wave & 1;   // 2x2 wave grid
    int bm = blockIdx.y * BM;
    int bn = blockIdx.x * BN;

    f32x4 acc[4][4] = {};

    int srow = lane >> 2;            // 0..15: row within 16-row staging chunk
    int scol = (lane & 3) * 8;       // 0,8,16,24: elem col

    for (int k0 = 0; k0 < DIM; k0 += BK) {
        __syncthreads();   // previous iteration's LDS reads complete
        #pragma unroll
        for (int t2 = 0; t2 < 2; ++t2) {
            int r = wave * 32 + t2 * 16;                     // wave-uniform
            const ushort_t* gA = A  + (size_t)(bm + r + srow) * DIM + k0 + scol;
            const ushort_t* gB = Wb + (size_t)(bn + r + srow) * DIM + k0 + scol;
            __builtin_amdgcn_global_load_lds(
                (const __attribute__((address_space(1))) void*)gA,
                (__attribute__((address_space(3))) void*)(sA + r * BK), 16, 0, 0);
            __builtin_amdgcn_global_load_lds(
                (const __attribute__((address_space(1))) void*)gB,
                (__attribute__((address_space(3))) void*)(sB + r * BK), 16, 0, 0);
        }
        __syncthreads();   // drains vmcnt(0) before barrier => LDS ready

        int q = lane >> 4;        // quad 0..3 -> k-offset q*8
        int rr = lane & 15;       // row within 16
        bf16x8 af[4], bfr[4];
        #pragma unroll
        for (int mi = 0; mi < 4; ++mi)
            af[mi] = *(const bf16x8*)(sA + (wm * 64 + mi * 16 + rr) * BK + q * 8);
        #pragma unroll
        for (int ni = 0; ni < 4; ++ni)
            bfr[ni] = *(const bf16x8*)(sB + (wn * 64 + ni * 16 + rr) * BK + q * 8);
        #pragma unroll
        for (int mi = 0; mi < 4; ++mi)
            #pragma unroll
            for (int ni = 0; ni < 4; ++ni)
                acc[mi][ni] = __builtin_amdgcn_mfma_f32_16x16x32_bf16(
                    af[mi], bfr[ni], acc[mi][ni], 0, 0, 0);
    }

    // Epilogue. C/D layout (verified m89/m91): col = lane&15, row = (lane>>4)*4 + reg
    int q = lane >> 4, nlane = lane & 15;
    #pragma unroll
    for (int ni = 0; ni < 4; ++ni) {
        int n_g = bn + wn * 64 + ni * 16 + nlane;
        float ws = wsum[n_g];
        float bs = bias[n_g];
        #pragma unroll
        for (int mi = 0; mi < 4; ++mi) {
            int m_base = bm + wm * 64 + mi * 16 + q * 4;
            #pragma unroll
            for (int r = 0; r < 4; ++r) {
                int m_g = m_base + r;
                float c = cvals ? cvals[m_g] : 0.f;
                float v = acc[mi][ni][r] + c * ws + bs;
                out[(size_t)m_g * OUTSTRIDE + n_g] = v;
                if (xb_next)
                    xb_next[(size_t)m_g * DIM + n_g] = f32_to_bf16(v);
            }
        }
    }
}

// ---------------------------------------------------------------------------
extern "C" void kernel_launch(void* const* d_in, const int* in_sizes, int n_in,
                              void* d_out, int out_size, void* d_ws, size_t ws_size,
                              hipStream_t stream) {
    (void)in_sizes; (void)n_in; (void)out_size; (void)ws_size;
    const float* x0   = (const float*)d_in[0];
    const float* W    = (const float*)d_in[1];
    const float* bias = (const float*)d_in[2];
    float* out = (float*)d_out;

    char* ws = (char*)d_ws;
    // workspace layout (bytes):
    //   xb   : 4 * 16384*512 * 2 = 67,108,864
    //   Wb   : 4 * 512*512  * 2 =  2,097,152
    //   wsum : 4 * 512 * 4      =      8,192
    //   sums : 4 * 16384 * 4    =    262,144
    //   cvals: 4 * 16384 * 4    =    262,144   (~66.5 MB total)
    ushort_t* xb   = (ushort_t*)ws;
    ushort_t* Wb   = (ushort_t*)(ws + 67108864);
    float*    wsum = (float*)   (ws + 69206016);
    float*    sums = (float*)   (ws + 69214208);
    float*    cvals= (float*)   (ws + 69476352);

    convw_kernel<<<NL * DIM, 256, 0, stream>>>(W, Wb, wsum);
    conv0_kernel<<<BROWS / 4, 256, 0, stream>>>(x0, xb, sums);

    dim3 ggrid(DIM / BN, BROWS / BM);   // (4, 128)
    for (int l = 0; l < NL; ++l) {
        gemm_kernel<<<ggrid, 256, 0, stream>>>(
            xb + (size_t)l * BROWS * DIM,
            Wb + (size_t)l * DIM * DIM,
            bias + l * DIM,
            wsum + l * DIM,
            (l > 0) ? (cvals + l * BROWS) : nullptr,
            out + l * DIM,
            (l < NL - 1) ? (xb + (size_t)(l + 1) * BROWS * DIM) : nullptr);
        if (l < NL - 1)
            dots_kernel<<<BROWS / 4, 256, 0, stream>>>(xb, sums, cvals, l + 1);
    }
}